// Round 5
// baseline (2371.147 us; speedup 1.0000x reference)
//
#include <hip/hip_runtime.h>
#include <math.h>

#define N 4096
#define STEPS 16384
#define CHUNK 16
#define NCHUNK (STEPS / CHUNK)
#define MBLK 1024
#define SST 20   // padded stride (floats) for ST/XT: float4-aligned, 2-way-bank max

// Workgroup barrier that does NOT drain vmcnt (LDS-only ordering between phases).
__device__ __forceinline__ void lgkm_barrier() {
  asm volatile("s_waitcnt lgkmcnt(0)\n\ts_barrier" ::: "memory");
}

// ---- prep: thr[t] = atanh(2u-1) in fp64; lastocc[t] = no later same-idx in chunk ----
__global__ __launch_bounds__(256) void pre_kernel(const float* __restrict__ u,
                                                  const int* __restrict__ idx,
                                                  double* __restrict__ thr,
                                                  int* __restrict__ lastocc) {
  int t = blockIdx.x * 256 + threadIdx.x;
  if (t < STEPS) {
    float r = 2.0f * u[t] - 1.0f;          // exact same fp32 rounding as reference
    double rd = (double)r;
    thr[t] = 0.5 * log((1.0 + rd) / (1.0 - rd));   // r=-1 -> -inf (tie->+1 matches ref)
    int cbase = t & ~(CHUNK - 1);
    int my = idx[t];
    int lo = 1;
    for (int tt = (t & (CHUNK - 1)) + 1; tt < CHUNK; ++tt)
      if (idx[cbase + tt] == my) { lo = 0; break; }
    lastocc[t] = lo;
  }
}

// ---- initial field: I0[row] = sum_k J[row,k]*m0[k] + h[row], fp64 accumulate ----
__global__ __launch_bounds__(256) void init_field_kernel(const float* __restrict__ J,
                                                         const float* __restrict__ h,
                                                         const float* __restrict__ m0,
                                                         double* __restrict__ I) {
  __shared__ double red[256];
  int row = blockIdx.x;
  const float4* Jr = (const float4*)(J + (size_t)row * N);
  const float4* mv = (const float4*)m0;
  double acc = 0.0;
  for (int q = threadIdx.x; q < N / 4; q += 256) {
    float4 a = Jr[q];
    float4 b = mv[q];
    acc += (double)(a.x * b.x) + (double)(a.y * b.y) +
           (double)(a.z * b.z) + (double)(a.w * b.w);
  }
  red[threadIdx.x] = acc;
  __syncthreads();
  for (int s = 128; s > 0; s >>= 1) {
    if (threadIdx.x < s) red[threadIdx.x] += red[threadIdx.x + s];
    __syncthreads();
  }
  if (threadIdx.x == 0) I[row] = red[0] + (double)h[row];
}

// ---- overlapped Glauber chain: 1 workgroup, 1024 threads, ONE barrier/chunk ----
// wave0 resolves chunk c concurrently with waves 1-15 applying chunk c-1:
//   base(c) = fbuf[c&1] (state <= c-2, stable: P2(c-1) writes the other parity)
//           + exact f64 correction X1(c) . delta(c-1)   (X1 prefetched, static addrs)
// P2 applies the compacted flip list of c-1 and ALWAYS writes through fbuf[(c-1)&1],
// so parity p always holds state <= c-2 at iteration c. Field ownership excludes
// wave0: threads 64..1023 own cols 256+4*(tid-64); threads 64..319 own col tid-64.
__global__ __launch_bounds__(MBLK) void pbit_kernel(const float* __restrict__ J,
                                                    const float* __restrict__ m0,
                                                    const int* __restrict__ idx,
                                                    const double* __restrict__ thr,
                                                    const int* __restrict__ lastocc,
                                                    const double* __restrict__ I0,
                                                    float* __restrict__ out) {
  __shared__ __align__(16) double fbuf_lds[2][N];       // 64 KB parity field buffers
  __shared__ __align__(16) float m_lds[N];              // 16 KB spins
  __shared__ __align__(16) float ST_lds[CHUNK * SST];   // S(c):  [col*SST+row]
  __shared__ __align__(16) float XT_lds[CHUNK * SST];   // X1(c): [col_c*SST+row_{c-1}]
  __shared__ __align__(16) int   pubi_lds[2][CHUNK];    // compacted flip rows
  __shared__ __align__(16) float pubd_lds[2][CHUNK];    // compacted deltas (+/-2)
  __shared__ __align__(16) float dvec_lds[CHUNK];       // uncompacted delta(c-1) (wave0-private)
  __shared__ int pubF_lds[2];                           // flip counts

  const int tid = threadIdx.x;
  const bool isW0 = (tid < 64);

  // ---- field ownership init (both parities = I0) ----
  double i0 = 0, i1 = 0, i2 = 0, i3 = 0, ix = 0;
  int cb = 0;
  if (!isW0) {
    cb = 256 + 4 * (tid - 64);
    const double* ip = I0 + cb;
    i0 = ip[0]; i1 = ip[1]; i2 = ip[2]; i3 = ip[3];
    *(double2*)(&fbuf_lds[0][cb + 0]) = make_double2(i0, i1);
    *(double2*)(&fbuf_lds[0][cb + 2]) = make_double2(i2, i3);
    *(double2*)(&fbuf_lds[1][cb + 0]) = make_double2(i0, i1);
    *(double2*)(&fbuf_lds[1][cb + 2]) = make_double2(i2, i3);
    if (tid < 320) {
      ix = I0[tid - 64];
      fbuf_lds[0][tid - 64] = ix;
      fbuf_lds[1][tid - 64] = ix;
    }
  }
  ((float4*)m_lds)[tid] = ((const float4*)m0)[tid];

  const int t16 = tid & 15;       // step slot within chunk
  const int gt = tid >> 2;        // gather row slot (wave0: 0..15)
  const int gq = (tid & 3) * 4;   // gather col group

  int mi = 0, ni = 0, mlo = 0, nlo = 0;
  double mt = 0.0, nt = 0.0;
  int growS = 0, growX = 0, gc0 = 0, gc1 = 0, gc2 = 0, gc3 = 0;
  float mym = 0.0f;

  if (isW0) {
    mi = idx[t16];      mt = thr[t16];      mlo = lastocc[t16];
    ni = idx[16 + t16]; nt = thr[16 + t16]; nlo = lastocc[16 + t16];
    growS = idx[16 + gt];        // S(1) rows = idx_1
    growX = idx[gt];             // X1(1) rows = idx_0
    gc0 = idx[16 + gq];     gc1 = idx[16 + gq + 1];
    gc2 = idx[16 + gq + 2]; gc3 = idx[16 + gq + 3];
    // synchronous S(0) gather (column-major, padded stride)
    int r0 = idx[gt];
    int c0 = idx[gq], c1 = idx[gq + 1], c2 = idx[gq + 2], c3 = idx[gq + 3];
    const float* Jr = J + (size_t)r0 * N;
    ST_lds[(gq + 0) * SST + gt] = Jr[c0];
    ST_lds[(gq + 1) * SST + gt] = Jr[c1];
    ST_lds[(gq + 2) * SST + gt] = Jr[c2];
    ST_lds[(gq + 3) * SST + gt] = Jr[c3];
    // zero XT (iter 0 multiplies it by dvec=0; must not be NaN garbage)
    for (int k = tid; k < CHUNK * SST; k += 64) XT_lds[k] = 0.0f;
    if (tid < 16) dvec_lds[t16] = 0.0f;
    if (tid == 0) { pubF_lds[0] = 0; pubF_lds[1] = 0; }
  }
  __syncthreads();
  if (isW0) mym = m_lds[mi];

  for (int c = 0; c < NCHUNK; ++c) {
    const int cpar = c & 1;

    if (isW0) {
      // ---- resolve chunk c (concurrent with P2 applying c-1) ----
      // 1) issue S(c+1)/X1(c+1) gathers (stored at end of this iter, used next)
      const float* Sp = J + (size_t)growS * N;
      float gs0 = Sp[gc0], gs1 = Sp[gc1], gs2 = Sp[gc2], gs3 = Sp[gc3];
      const float* Xp = J + (size_t)growX * N;
      float gx0 = Xp[gc0], gx1 = Xp[gc1], gx2 = Xp[gc2], gx3 = Xp[gc3];
      // 2) staged idx/thr/lastocc loads for c+2
      int b2 = c * CHUNK + 32;
      if (b2 >= STEPS) b2 = 0;   // clamp: values unused on final chunks
      int n2i = idx[b2 + t16];
      double n2t = thr[b2 + t16];
      int n2lo = lastocc[b2 + t16];
      int g2row = idx[b2 + gt];
      int g2c0 = idx[b2 + gq];     int g2c1 = idx[b2 + gq + 1];
      int g2c2 = idx[b2 + gq + 2]; int g2c3 = idx[b2 + gq + 3];
      // 3) LDS reads: Scol, X1 row, delta(c-1), base field (state <= c-2)
      const float* sp = &ST_lds[t16 * SST];
      float4 sa = *(const float4*)(sp + 0);
      float4 sb = *(const float4*)(sp + 4);
      float4 sc = *(const float4*)(sp + 8);
      float4 sd = *(const float4*)(sp + 12);
      const float* xq = &XT_lds[t16 * SST];
      float4 xa = *(const float4*)(xq + 0);
      float4 xb = *(const float4*)(xq + 4);
      float4 xc = *(const float4*)(xq + 8);
      float4 xd = *(const float4*)(xq + 12);
      float4 da = *(const float4*)(dvec_lds + 0);
      float4 db = *(const float4*)(dvec_lds + 4);
      float4 dc = *(const float4*)(dvec_lds + 8);
      float4 dd = *(const float4*)(dvec_lds + 12);
      double Ival = fbuf_lds[cpar][mi];
      // exact f64 correction: products exact in fp32 (delta in {-2,0,2}),
      // 16-term f64 sum of 25-bit values is exact
      double corr = (double)(xa.x * da.x) + (double)(xa.y * da.y)
                  + (double)(xa.z * da.z) + (double)(xa.w * da.w)
                  + (double)(xb.x * db.x) + (double)(xb.y * db.y)
                  + (double)(xb.z * db.z) + (double)(xb.w * db.w)
                  + (double)(xc.x * dc.x) + (double)(xc.y * dc.y)
                  + (double)(xc.z * dc.z) + (double)(xc.w * dc.w)
                  + (double)(xd.x * dd.x) + (double)(xd.y * dd.y)
                  + (double)(xd.z * dd.z) + (double)(xd.w * dd.w);
      Ival += corr;

      // 4) flip-driven serial resolve: rounds = flips + 1
      float mcur = mym;
      float finals = 0.0f, finald = 0.0f;
      int conf = -1;
      bool locked = false;
      while (true) {
        float s = (Ival >= mt) ? 1.0f : -1.0f;   // I >= atanh(r) <=> tanh(I) >= r
        float dl = s - mcur;
        unsigned long long mask = __ballot(dl != 0.0f) & 0xFFFFull;
        mask &= (~0ull) << (conf + 1);
        if (mask == 0) {
          if (!locked) { finals = s; finald = 0.0f; }
          break;
        }
        int f = (int)__builtin_ctzll(mask);      // wave-uniform
        if (!locked && t16 <= f) { finals = s; finald = dl; locked = true; }
        float dl_f = __int_as_float(__builtin_amdgcn_readlane(__float_as_int(dl), f));
        float s_f  = __int_as_float(__builtin_amdgcn_readlane(__float_as_int(s), f));
        int   i_f  = __builtin_amdgcn_readlane(mi, f);
        float xcol;                               // Scol[f], f uniform
        switch (f) {
          case 0:  xcol = sa.x; break;  case 1:  xcol = sa.y; break;
          case 2:  xcol = sa.z; break;  case 3:  xcol = sa.w; break;
          case 4:  xcol = sb.x; break;  case 5:  xcol = sb.y; break;
          case 6:  xcol = sb.z; break;  case 7:  xcol = sb.w; break;
          case 8:  xcol = sc.x; break;  case 9:  xcol = sc.y; break;
          case 10: xcol = sc.z; break;  case 11: xcol = sc.w; break;
          case 12: xcol = sd.x; break;  case 13: xcol = sd.y; break;
          default: xcol = (f == 14) ? sd.z : sd.w; break;
        }
        Ival += (double)(xcol * dl_f);            // exact product: dl in {-2,2}
        if (mi == i_f) mcur = s_f;                // in-chunk duplicate index
        conf = f;
      }
      // 5) publish: compacted flip list (parity c), dvec, m updates
      unsigned long long fm = __ballot((tid < 16) && (finald != 0.0f));
      if (tid < 16) {
        dvec_lds[t16] = finald;
        if (finald != 0.0f) {
          int pos = __popcll(fm & ((1ull << t16) - 1ull));
          pubi_lds[cpar][pos] = mi;
          pubd_lds[cpar][pos] = finald;
        }
        if (mlo) m_lds[mi] = finals;
        if (tid == 0) pubF_lds[cpar] = __popcll(fm);
      }
      // 6) store gathered S(c+1)/X1(c+1) (waits the vmcnt of step 1)
      ST_lds[(gq + 0) * SST + gt] = gs0;
      ST_lds[(gq + 1) * SST + gt] = gs1;
      ST_lds[(gq + 2) * SST + gt] = gs2;
      ST_lds[(gq + 3) * SST + gt] = gs3;
      XT_lds[(gq + 0) * SST + gt] = gx0;
      XT_lds[(gq + 1) * SST + gt] = gx1;
      XT_lds[(gq + 2) * SST + gt] = gx2;
      XT_lds[(gq + 3) * SST + gt] = gx3;
      // 7) m gather for next chunk (after this chunk's m writes; in-order)
      mym = m_lds[ni];
      // 8) rotate pipeline registers
      mi = ni; mt = nt; mlo = nlo;
      ni = n2i; nt = n2t; nlo = n2lo;
      growX = growS; growS = g2row;
      gc0 = g2c0; gc1 = g2c1; gc2 = g2c2; gc3 = g2c3;
    } else {
      // ---- apply chunk c-1 (parity cpar^1) ----
      const int pp = cpar ^ 1;
      int F = pubF_lds[pp];
      if (F > 0) {                         // uniform: skip flip-free chunks
        int4 ra = *(const int4*)(&pubi_lds[pp][0]);
        int4 rb = *(const int4*)(&pubi_lds[pp][4]);
        int4 rc = *(const int4*)(&pubi_lds[pp][8]);
        int4 rd = *(const int4*)(&pubi_lds[pp][12]);
        float4 pa = *(const float4*)(&pubd_lds[pp][0]);
        float4 pb = *(const float4*)(&pubd_lds[pp][4]);
        float4 pc = *(const float4*)(&pubd_lds[pp][8]);
        float4 pd = *(const float4*)(&pubd_lds[pp][12]);
        int rows[CHUNK] = {ra.x, ra.y, ra.z, ra.w, rb.x, rb.y, rb.z, rb.w,
                           rc.x, rc.y, rc.z, rc.w, rd.x, rd.y, rd.z, rd.w};
        float dv[CHUNK] = {pa.x, pa.y, pa.z, pa.w, pb.x, pb.y, pb.z, pb.w,
                           pc.x, pc.y, pc.z, pc.w, pd.x, pd.y, pd.z, pd.w};
        float a0 = 0.f, a1 = 0.f, a2 = 0.f, a3 = 0.f, ax = 0.f;
        {
          float4 rv[8]; float rvx[8];
#pragma unroll
          for (int t = 0; t < 8; ++t)
            if (t < F) {
              const float* rp = J + (size_t)rows[t] * N;
              rv[t] = *(const float4*)(rp + cb);
              if (tid < 320) rvx[t] = rp[tid - 64];
            }
#pragma unroll
          for (int t = 0; t < 8; ++t)
            if (t < F) {
              a0 += rv[t].x * dv[t]; a1 += rv[t].y * dv[t];
              a2 += rv[t].z * dv[t]; a3 += rv[t].w * dv[t];
              if (tid < 320) ax += rvx[t] * dv[t];
            }
        }
        if (F > 8) {
          float4 rv[8]; float rvx[8];
#pragma unroll
          for (int t = 8; t < 16; ++t)
            if (t < F) {
              const float* rp = J + (size_t)rows[t] * N;
              rv[t - 8] = *(const float4*)(rp + cb);
              if (tid < 320) rvx[t - 8] = rp[tid - 64];
            }
#pragma unroll
          for (int t = 8; t < 16; ++t)
            if (t < F) {
              a0 += rv[t - 8].x * dv[t]; a1 += rv[t - 8].y * dv[t];
              a2 += rv[t - 8].z * dv[t]; a3 += rv[t - 8].w * dv[t];
              if (tid < 320) ax += rvx[t - 8] * dv[t];
            }
        }
        // chunk-local exact fp32 partials -> fp64 master
        i0 += (double)a0; i1 += (double)a1; i2 += (double)a2; i3 += (double)a3;
        if (tid < 320) ix += (double)ax;
      }
      // ALWAYS write-through (keeps parity pp = state <= c-1 even when F==0)
      *(double2*)(&fbuf_lds[pp][cb + 0]) = make_double2(i0, i1);
      *(double2*)(&fbuf_lds[pp][cb + 2]) = make_double2(i2, i3);
      if (tid < 320) fbuf_lds[pp][tid - 64] = ix;
    }
    lgkm_barrier();
  }

  ((float4*)out)[tid] = ((const float4*)m_lds)[tid];
}

extern "C" void kernel_launch(void* const* d_in, const int* in_sizes, int n_in,
                              void* d_out, int out_size, void* d_ws, size_t ws_size,
                              hipStream_t stream) {
  const float* J = (const float*)d_in[0];
  const float* h = (const float*)d_in[1];
  const float* m0 = (const float*)d_in[2];
  const int* idx = (const int*)d_in[3];
  const float* u = (const float*)d_in[4];
  float* out = (float*)d_out;

  double* thr = (double*)d_ws;                                        // 16384 f64
  double* I0 = (double*)((char*)d_ws + STEPS * sizeof(double));       // 4096 f64
  int* lastocc = (int*)((char*)d_ws + STEPS * sizeof(double)
                                    + N * sizeof(double));            // 16384 i32

  pre_kernel<<<dim3(STEPS / 256), dim3(256), 0, stream>>>(u, idx, thr, lastocc);
  init_field_kernel<<<dim3(N), dim3(256), 0, stream>>>(J, h, m0, I0);
  pbit_kernel<<<dim3(1), dim3(MBLK), 0, stream>>>(J, m0, idx, thr, lastocc, I0, out);
}

// Round 6
// 2262.737 us; speedup vs baseline: 1.0479x; 1.0479x over previous
//
#include <hip/hip_runtime.h>
#include <math.h>

#define N 4096
#define STEPS 16384
#define CHUNK 16
#define NCHUNK (STEPS / CHUNK)
#define MBLK 1024
#define SST 20   // padded stride (floats) for ST: float4-aligned, mild bank spread

// Workgroup barrier that does NOT drain vmcnt (LDS-only ordering between phases).
__device__ __forceinline__ void lgkm_barrier() {
  asm volatile("s_waitcnt lgkmcnt(0)\n\ts_barrier" ::: "memory");
}

// ---- prep: thr[t] = atanh(2u-1) in fp64; lastocc[t] = no later same-idx in chunk ----
__global__ __launch_bounds__(256) void pre_kernel(const float* __restrict__ u,
                                                  const int* __restrict__ idx,
                                                  double* __restrict__ thr,
                                                  int* __restrict__ lastocc) {
  int t = blockIdx.x * 256 + threadIdx.x;
  if (t < STEPS) {
    float r = 2.0f * u[t] - 1.0f;          // exact same fp32 rounding as reference
    double rd = (double)r;
    thr[t] = 0.5 * log((1.0 + rd) / (1.0 - rd));   // r=-1 -> -inf (tie->+1 matches ref)
    int cbase = t & ~(CHUNK - 1);
    int my = idx[t];
    int lo = 1;
    for (int tt = (t & (CHUNK - 1)) + 1; tt < CHUNK; ++tt)
      if (idx[cbase + tt] == my) { lo = 0; break; }
    lastocc[t] = lo;
  }
}

// ---- initial field: I0[row] = sum_k J[row,k]*m0[k] + h[row], fp64 accumulate ----
__global__ __launch_bounds__(256) void init_field_kernel(const float* __restrict__ J,
                                                         const float* __restrict__ h,
                                                         const float* __restrict__ m0,
                                                         double* __restrict__ I) {
  __shared__ double red[256];
  int row = blockIdx.x;
  const float4* Jr = (const float4*)(J + (size_t)row * N);
  const float4* mv = (const float4*)m0;
  double acc = 0.0;
  for (int q = threadIdx.x; q < N / 4; q += 256) {
    float4 a = Jr[q];
    float4 b = mv[q];
    acc += (double)(a.x * b.x) + (double)(a.y * b.y) +
           (double)(a.z * b.z) + (double)(a.w * b.w);
  }
  red[threadIdx.x] = acc;
  __syncthreads();
  for (int s = 128; s > 0; s >>= 1) {
    if (threadIdx.x < s) red[threadIdx.x] += red[threadIdx.x + s];
    __syncthreads();
  }
  if (threadIdx.x == 0) I[row] = red[0] + (double)h[row];
}

// ---- chunk-resolved Glauber chain: 1 workgroup, 1024 threads ----
// P1: wave0 resolves 16 steps flip-driven (rounds = flips+1). The 16x16 coupling
//     matrix S(c) is gathered TWO chunks ahead: issued in P1(c-2), stored to the
//     double-buffered ST in P1(c-1) (vmcnt landed -> no stall), read in P1(c).
// P2: waves 1-15 apply the compacted flip list (wave0 owns no field -> its chunk
//     path is resolve-only). fp64 register field + LDS write-through.
// Barriers are lgkm-only so wave0's gather loads survive them.
__global__ __launch_bounds__(MBLK) void pbit_kernel(const float* __restrict__ J,
                                                    const float* __restrict__ m0,
                                                    const int* __restrict__ idx,
                                                    const double* __restrict__ thr,
                                                    const int* __restrict__ lastocc,
                                                    const double* __restrict__ I0,
                                                    float* __restrict__ out) {
  __shared__ __align__(16) double field_lds[N];          // 32 KB master field
  __shared__ __align__(16) float m_lds[N];               // 16 KB spins
  __shared__ __align__(16) float ST_lds[2][CHUNK * SST]; // S double buffer
  __shared__ __align__(16) int   pubi_lds[CHUNK];        // compacted flip rows
  __shared__ __align__(16) float pubd_lds[CHUNK];        // compacted deltas (+/-2)
  __shared__ int pubF_lds;                               // flip count

  const int tid = threadIdx.x;
  const bool isW0 = (tid < 64);

  // ---- field ownership (wave0 excluded): threads 64..1023 own cols
  // 256+4*(tid-64)..+3; threads 64..319 additionally own col tid-64.
  double i0 = 0, i1 = 0, i2 = 0, i3 = 0, ix = 0;
  int cb = 0;
  if (!isW0) {
    cb = 256 + 4 * (tid - 64);
    const double* ip = I0 + cb;
    i0 = ip[0]; i1 = ip[1]; i2 = ip[2]; i3 = ip[3];
    *(double2*)(&field_lds[cb + 0]) = make_double2(i0, i1);
    *(double2*)(&field_lds[cb + 2]) = make_double2(i2, i3);
    if (tid < 320) { ix = I0[tid - 64]; field_lds[tid - 64] = ix; }
  }
  ((float4*)m_lds)[tid] = ((const float4*)m0)[tid];

  const int t16 = tid & 15;       // step slot within chunk
  const int gt = tid >> 2;        // gather row slot (wave0: 0..15)
  const int gq = (tid & 3) * 4;   // gather col group

  // wave0 pipeline registers:
  //   t16-view stages: L0 = chunk c (mi/mt/mlo), L1 = c+1, L2 = c+2
  //   gather-addr stage: chunk c+2 (grow2/g2c*)
  //   gather values pv = S(c+1) (issued P1(c-1), stored P1(c))
  int mi = 0, ni = 0, n2i = 0, mlo = 0, nlo = 0, n2lo = 0;
  double mt = 0.0, nt = 0.0, n2t = 0.0;
  int grow2 = 0, g2c0 = 0, g2c1 = 0, g2c2 = 0, g2c3 = 0;
  float pv0 = 0.f, pv1 = 0.f, pv2 = 0.f, pv3 = 0.f;
  float mym = 0.0f;

  if (isW0) {
    mi  = idx[t16];      mt  = thr[t16];      mlo  = lastocc[t16];
    ni  = idx[16 + t16]; nt  = thr[16 + t16]; nlo  = lastocc[16 + t16];
    n2i = idx[32 + t16]; n2t = thr[32 + t16]; n2lo = lastocc[32 + t16];
    grow2 = idx[32 + gt];
    g2c0 = idx[32 + gq];     g2c1 = idx[32 + gq + 1];
    g2c2 = idx[32 + gq + 2]; g2c3 = idx[32 + gq + 3];
    // synchronous gather S(0) -> buf 0
    int r0 = idx[gt];
    int c0 = idx[gq], c1 = idx[gq + 1], c2 = idx[gq + 2], c3 = idx[gq + 3];
    const float* Jr = J + (size_t)r0 * N;
    ST_lds[0][(gq + 0) * SST + gt] = Jr[c0];
    ST_lds[0][(gq + 1) * SST + gt] = Jr[c1];
    ST_lds[0][(gq + 2) * SST + gt] = Jr[c2];
    ST_lds[0][(gq + 3) * SST + gt] = Jr[c3];
    // async issue pv = S(1) (stored into buf1 in P1(0); waited there)
    int r1 = idx[16 + gt];
    int c10 = idx[16 + gq],     c11 = idx[16 + gq + 1];
    int c12 = idx[16 + gq + 2], c13 = idx[16 + gq + 3];
    const float* J1 = J + (size_t)r1 * N;
    pv0 = J1[c10]; pv1 = J1[c11]; pv2 = J1[c12]; pv3 = J1[c13];
    if (tid == 0) pubF_lds = 0;
  }
  __syncthreads();
  if (isW0) mym = m_lds[mi];

  for (int c = 0; c < NCHUNK; ++c) {
    // ---------------- P1: wave 0 resolves the 16 decisions ----------------
    if (isW0) {
      // 1) issue gather cv = S(c+2) (addrs staged last chunk; consumed P1(c+2))
      const float* Jg = J + (size_t)grow2 * N;
      float cv0 = Jg[g2c0], cv1 = Jg[g2c1], cv2 = Jg[g2c2], cv3 = Jg[g2c3];
      // 2) issue staged loads for chunk c+3 (t16-view + gather-view)
      int b3 = c * CHUNK + 48;
      if (b3 >= STEPS) b3 = 0;   // clamp: values unused on final chunks
      int L3i = idx[b3 + t16];
      double L3t = thr[b3 + t16];
      int L3lo = lastocc[b3 + t16];
      int L3grow = idx[b3 + gt];
      int L3c0 = idx[b3 + gq];     int L3c1 = idx[b3 + gq + 1];
      int L3c2 = idx[b3 + gq + 2]; int L3c3 = idx[b3 + gq + 3];
      // 3) read base field + this chunk's Scol from buf[c&1]
      double Ival = field_lds[mi];
      const float* sp = &ST_lds[c & 1][t16 * SST];
      float4 sa = *(const float4*)(sp + 0);
      float4 sb = *(const float4*)(sp + 4);
      float4 sc = *(const float4*)(sp + 8);
      float4 sd = *(const float4*)(sp + 12);
      // 4) store pv = S(c+1) into buf[(c+1)&1] (vmcnt: issued a full chunk ago)
      ST_lds[(c + 1) & 1][(gq + 0) * SST + gt] = pv0;
      ST_lds[(c + 1) & 1][(gq + 1) * SST + gt] = pv1;
      ST_lds[(c + 1) & 1][(gq + 2) * SST + gt] = pv2;
      ST_lds[(c + 1) & 1][(gq + 3) * SST + gt] = pv3;
      // 5) flip-driven serial resolve: rounds = flips + 1
      float mcur = mym;
      float finals = 0.0f, finald = 0.0f;
      int conf = -1;
      bool locked = false;
      while (true) {
        float s = (Ival >= mt) ? 1.0f : -1.0f;   // I >= atanh(r) <=> tanh(I) >= r
        float dl = s - mcur;
        unsigned long long mask = __ballot(dl != 0.0f) & 0xFFFFull;
        mask &= (~0ull) << (conf + 1);
        if (mask == 0) {
          if (!locked) { finals = s; finald = 0.0f; }
          break;
        }
        int f = (int)__builtin_ctzll(mask);      // wave-uniform
        if (!locked && t16 <= f) { finals = s; finald = dl; locked = true; }
        float dl_f = __int_as_float(__builtin_amdgcn_readlane(__float_as_int(dl), f));
        float s_f  = __int_as_float(__builtin_amdgcn_readlane(__float_as_int(s), f));
        int   i_f  = __builtin_amdgcn_readlane(mi, f);
        // branchless Scol[f] select (cndmask tree, no scalar jump on the chain)
        float4 ph = (f & 8) ? ((f & 4) ? sd : sc) : ((f & 4) ? sb : sa);
        float xcol = (f & 2) ? ((f & 1) ? ph.w : ph.z)
                             : ((f & 1) ? ph.y : ph.x);
        Ival += (double)(xcol * dl_f);            // exact product: dl in {-2,2}
        if (mi == i_f) mcur = s_f;                // in-chunk duplicate index
        conf = f;
      }
      // 6) publish: compacted flip list + m updates (last occurrence wins)
      unsigned long long fm = __ballot((tid < 16) && (finald != 0.0f));
      if (tid < 16) {
        if (finald != 0.0f) {
          int pos = __popcll(fm & ((1ull << t16) - 1ull));
          pubi_lds[pos] = mi;
          pubd_lds[pos] = finald;
        }
        if (mlo) m_lds[mi] = finals;
        if (tid == 0) pubF_lds = __popcll(fm);
      }
      // 7) m gather for next chunk (after this chunk's m writes; in-order)
      mym = m_lds[ni];
      // 8) rotate pipeline registers
      mi = ni; mt = nt; mlo = nlo;
      ni = n2i; nt = n2t; nlo = n2lo;
      n2i = L3i; n2t = L3t; n2lo = L3lo;
      grow2 = L3grow;
      g2c0 = L3c0; g2c1 = L3c1; g2c2 = L3c2; g2c3 = L3c3;
      pv0 = cv0; pv1 = cv1; pv2 = cv2; pv3 = cv3;
    }
    lgkm_barrier();

    // ---------------- P2: waves 1-15 apply the F flipped rows ----------------
    if (!isW0) {
      int F = pubF_lds;
      if (F > 0) {                         // uniform: skip flip-free chunks
        int4 ra = *(const int4*)(pubi_lds + 0);
        int4 rb = *(const int4*)(pubi_lds + 4);
        int4 rc = *(const int4*)(pubi_lds + 8);
        int4 rd = *(const int4*)(pubi_lds + 12);
        float4 pa = *(const float4*)(pubd_lds + 0);
        float4 pb = *(const float4*)(pubd_lds + 4);
        float4 pc = *(const float4*)(pubd_lds + 8);
        float4 pd = *(const float4*)(pubd_lds + 12);
        int rows[CHUNK] = {ra.x, ra.y, ra.z, ra.w, rb.x, rb.y, rb.z, rb.w,
                           rc.x, rc.y, rc.z, rc.w, rd.x, rd.y, rd.z, rd.w};
        float dv[CHUNK] = {pa.x, pa.y, pa.z, pa.w, pb.x, pb.y, pb.z, pb.w,
                           pc.x, pc.y, pc.z, pc.w, pd.x, pd.y, pd.z, pd.w};
        float a0 = 0.f, a1 = 0.f, a2 = 0.f, a3 = 0.f, ax = 0.f;
        {
          float4 rv[8]; float rvx[8];
#pragma unroll
          for (int t = 0; t < 8; ++t)
            if (t < F) {
              const float* rp = J + (size_t)rows[t] * N;
              rv[t] = *(const float4*)(rp + cb);
              if (tid < 320) rvx[t] = rp[tid - 64];
            }
#pragma unroll
          for (int t = 0; t < 8; ++t)
            if (t < F) {
              a0 += rv[t].x * dv[t]; a1 += rv[t].y * dv[t];
              a2 += rv[t].z * dv[t]; a3 += rv[t].w * dv[t];
              if (tid < 320) ax += rvx[t] * dv[t];
            }
        }
        if (F > 8) {
          float4 rv[8]; float rvx[8];
#pragma unroll
          for (int t = 8; t < 16; ++t)
            if (t < F) {
              const float* rp = J + (size_t)rows[t] * N;
              rv[t - 8] = *(const float4*)(rp + cb);
              if (tid < 320) rvx[t - 8] = rp[tid - 64];
            }
#pragma unroll
          for (int t = 8; t < 16; ++t)
            if (t < F) {
              a0 += rv[t - 8].x * dv[t]; a1 += rv[t - 8].y * dv[t];
              a2 += rv[t - 8].z * dv[t]; a3 += rv[t - 8].w * dv[t];
              if (tid < 320) ax += rvx[t - 8] * dv[t];
            }
        }
        // chunk-local exact fp32 partials -> fp64 master, write-through to LDS
        i0 += (double)a0; i1 += (double)a1; i2 += (double)a2; i3 += (double)a3;
        *(double2*)(&field_lds[cb + 0]) = make_double2(i0, i1);
        *(double2*)(&field_lds[cb + 2]) = make_double2(i2, i3);
        if (tid < 320) { ix += (double)ax; field_lds[tid - 64] = ix; }
      }
    }
    lgkm_barrier();
  }

  ((float4*)out)[tid] = ((const float4*)m_lds)[tid];
}

extern "C" void kernel_launch(void* const* d_in, const int* in_sizes, int n_in,
                              void* d_out, int out_size, void* d_ws, size_t ws_size,
                              hipStream_t stream) {
  const float* J = (const float*)d_in[0];
  const float* h = (const float*)d_in[1];
  const float* m0 = (const float*)d_in[2];
  const int* idx = (const int*)d_in[3];
  const float* u = (const float*)d_in[4];
  float* out = (float*)d_out;

  double* thr = (double*)d_ws;                                        // 16384 f64
  double* I0 = (double*)((char*)d_ws + STEPS * sizeof(double));       // 4096 f64
  int* lastocc = (int*)((char*)d_ws + STEPS * sizeof(double)
                                    + N * sizeof(double));            // 16384 i32

  pre_kernel<<<dim3(STEPS / 256), dim3(256), 0, stream>>>(u, idx, thr, lastocc);
  init_field_kernel<<<dim3(N), dim3(256), 0, stream>>>(J, h, m0, I0);
  pbit_kernel<<<dim3(1), dim3(MBLK), 0, stream>>>(J, m0, idx, thr, lastocc, I0, out);
}